// Round 15
// baseline (109.952 us; speedup 1.0000x reference)
//
#include <hip/hip_runtime.h>
#include <math.h>

#define NN 4096
#define MM 32
#define LOG2F_ 0.69314718055994530942f

typedef __attribute__((ext_vector_type(8))) short short8;
typedef __attribute__((ext_vector_type(4))) float f32x4;

__device__ __forceinline__ float ssp_fast(float x) {
    float sp = (x > 20.0f) ? x : __logf(1.0f + __expf(x));
    return sp - LOG2F_;
}

// float -> bf16 bits, round-to-nearest-even
__device__ __forceinline__ short f2bf(float x) {
    unsigned u = __float_as_uint(x);
    unsigned r = (u + 0x7FFFu + ((u >> 16) & 1u)) >> 16;
    return (short)r;
}
__device__ __forceinline__ float bf2f(short s) {
    return __uint_as_float(((unsigned)(unsigned short)s) << 16);
}

// K1: pre = ielin(feat, w_pre0, w_pre1) via MFMA, 8 nodes/block.
// Weight->bf16^T conversion spread across all blocks (<=1 elem/thread).
__global__ __launch_bounds__(256) void pre_kernel(
    const float* __restrict__ feat, const float* __restrict__ w0,
    const float* __restrict__ w1, float* __restrict__ pre_t,
    const float* __restrict__ w_f1, const float* __restrict__ w_f2,
    const float* __restrict__ w_a0, const float* __restrict__ w_a1,
    const float* __restrict__ w_b0, const float* __restrict__ w_b1,
    short* __restrict__ w1t, short* __restrict__ w2t,
    short* __restrict__ w_a0t, short* __restrict__ w_a1t,
    short* __restrict__ w_b0t, short* __restrict__ w_b1t)
{
    int t = threadIdx.x;
    int base = blockIdx.x * 8;
    int lane = t & 63, wave = t >> 6, q = lane >> 4, nn = lane & 15;

    // distributed weight transpose+convert: gid in [0, 34816)
    {
        int gid = blockIdx.x * 256 + t;
        if (gid < 2048) {
            int n = gid >> 5, k = gid & 31;
            w1t[gid] = (k < 16) ? f2bf(w_f1[k * 64 + n]) : (short)0;
        } else if (gid < 6144) {
            int idx = gid - 2048; int n = idx >> 6, k = idx & 63;
            w2t[idx] = f2bf(w_f2[k * 64 + n]);
        } else if (gid < 10240) {
            int idx = gid - 6144; int n = idx >> 6, k = idx & 63;
            w_b0t[idx] = f2bf(w_b0[k * 64 + n]);
        } else if (gid < 14336) {
            int idx = gid - 10240; int n = idx >> 6, k = idx & 63;
            w_b1t[idx] = f2bf(w_b1[k * 64 + n]);
        } else if (gid < 22528) {
            int idx = gid - 14336; int n = idx >> 7, k = idx & 127;
            w_a0t[idx] = f2bf(w_a0[k * 64 + n]);
        } else if (gid < 34816) {
            int idx = gid - 22528; int n = idx / 192, k = idx - n * 192;
            w_a1t[idx] = f2bf(w_a1[k * 64 + n]);
        }
    }

    __shared__ __align__(16) short s_a0[16 * 72];
    __shared__ __align__(16) short s_a1[2][16 * 72];
    __shared__ __align__(16) short s_w0[64 * 72];
    __shared__ __align__(16) short s_w1[64 * 72];
    __shared__ __align__(16) float s_po[8][256];

    for (int idx = t; idx < 512; idx += 256) {
        int r = 8 + (idx >> 6), k = idx & 63;
        s_a0[r * 72 + k] = 0;
        s_a1[1][r * 72 + k] = 0;
    }
    #pragma unroll 4
    for (int kk = 0; kk < 16; ++kk) {
        int k = wave * 16 + kk;
        s_w0[lane * 72 + k] = f2bf(w0[k * 64 + lane]);
        s_w1[lane * 72 + k] = f2bf(w1[k * 64 + lane]);
    }
    {
        const float4* f4 = (const float4*)(feat + (size_t)base * 256);
        #pragma unroll
        for (int rep = 0; rep < 2; ++rep) {
            int idx = t + rep * 256;
            float4 v = f4[idx];
            int node = idx >> 6, c = (idx & 63) * 4;
            short* dst;
            if (c < 64) {
                dst = &s_a0[node * 72 + c];
            } else {
                int mm = (c >> 6) - 1, ch = c & 63;
                int row = node * 3 + mm;
                dst = &s_a1[row >> 4][(row & 15) * 72 + ch];
            }
            dst[0] = f2bf(v.x); dst[1] = f2bf(v.y);
            dst[2] = f2bf(v.z); dst[3] = f2bf(v.w);
        }
    }
    __syncthreads();

    short8 bw0[2], bw1[2];
    #pragma unroll
    for (int kc = 0; kc < 2; ++kc) {
        bw0[kc] = *(const short8*)&s_w0[(16 * wave + nn) * 72 + kc * 32 + q * 8];
        bw1[kc] = *(const short8*)&s_w1[(16 * wave + nn) * 72 + kc * 32 + q * 8];
    }
    {
        f32x4 acc = {0.f, 0.f, 0.f, 0.f};
        #pragma unroll
        for (int kc = 0; kc < 2; ++kc) {
            short8 a = *(const short8*)&s_a0[nn * 72 + kc * 32 + q * 8];
            acc = __builtin_amdgcn_mfma_f32_16x16x32_bf16(a, bw0[kc], acc, 0, 0, 0);
        }
        if (q < 2) {
            #pragma unroll
            for (int r = 0; r < 4; ++r)
                s_po[4 * q + r][(16 * wave + nn) * 4 + 0] = acc[r];
        }
    }
    #pragma unroll
    for (int tile = 0; tile < 2; ++tile) {
        f32x4 acc = {0.f, 0.f, 0.f, 0.f};
        #pragma unroll
        for (int kc = 0; kc < 2; ++kc) {
            short8 a = *(const short8*)&s_a1[tile][nn * 72 + kc * 32 + q * 8];
            acc = __builtin_amdgcn_mfma_f32_16x16x32_bf16(a, bw1[kc], acc, 0, 0, 0);
        }
        #pragma unroll
        for (int r = 0; r < 4; ++r) {
            int row = tile * 16 + 4 * q + r;
            if (row < 24) {
                unsigned node = (unsigned)row / 3u;
                int mm = row - (int)node * 3;
                s_po[node][(16 * wave + nn) * 4 + 1 + mm] = acc[r];
            }
        }
    }
    __syncthreads();

    #pragma unroll
    for (int rep = 0; rep < 2; ++rep) {
        int idx = t + rep * 256;
        int node = idx >> 6, c4 = idx & 63;
        *(float4*)&pre_t[(size_t)(base + node) * 256 + c4 * 4] =
            *(const float4*)&s_po[node][c4 * 4];
    }
}

// K2: WAVE-AUTONOMOUS, LDS-dieted. 4 nodes/block, each wave owns one node
// (32 edges) end-to-end. P3's filter matmul accumulates in REGISTERS and
// writes back over the dead h region -> per-wave LDS 4608 B, block 18.4 KB
// (was 36.9). 4 barriers total. launch_bounds(256,5).
__global__ __launch_bounds__(256, 5) void edge_kernel(
    const float* __restrict__ xyz, const float* __restrict__ feat,
    const float* __restrict__ pre_t,
    const short* __restrict__ w1t_g, const short* __restrict__ w2t_g,
    const short* __restrict__ w_a0t, const short* __restrict__ w_a1t,
    const short* __restrict__ w_b0t, const short* __restrict__ w_b1t,
    const int* __restrict__ src_idx, const int* __restrict__ edge_mask,
    float* __restrict__ out)
{
    int i0 = blockIdx.x * 4;
    int t = threadIdx.x;
    int lane = t & 63;
    int wave = t >> 6;
    int q = lane >> 4;
    int nn = lane & 15;

    __shared__ __align__(16) char s_u[18432];   // 4 x 4608 wave-private; P5 overlays
    short* s_hf = (short*)(s_u + wave * 4608);  // 32 x 72 bf16: h, then f

    int node = i0 + wave;

    // ---- geometry: lane handles edge lane&31 (2-way redundant) ----
    int e = lane & 31;
    int j = src_idx[node * MM + e];
    float msk = (float)edge_mask[node * MM + e];
    float r0 = xyz[j * 3 + 0] - xyz[node * 3 + 0];
    float r1 = xyz[j * 3 + 1] - xyz[node * 3 + 1];
    float r2 = xyz[j * 3 + 2] - xyz[node * 3 + 2];
    float d = sqrtf(r0 * r0 + r1 * r1 + r2 * r2);
    float inv_d = 1.0f / d;
    float x = d * 0.2f;
    float env = 0.f;
    if (x < 1.f) {
        float x3 = x * x * x;
        env = 1.f - 10.f * x3 + 15.f * x3 * x - 6.f * x3 * x * x;
    }
    float sc = env * inv_d;
    float ry = r1 * inv_d, rz = r2 * inv_d, rx = r0 * inv_d;

    // ---- prefetch gather groups 0,1 (edges 0-7) ----
    float4 pv[2][4];
    #pragma unroll
    for (int u = 0; u < 4; ++u) {
        int ju = __shfl(j, u, 64);
        pv[0][u] = ((const float4*)pre_t)[(size_t)ju * 64 + lane];
    }
    #pragma unroll
    for (int u = 0; u < 4; ++u) {
        int ju = __shfl(j, 4 + u, 64);
        pv[1][u] = ((const float4*)pre_t)[(size_t)ju * 64 + lane];
    }

    // ---- rbf A-fragments in registers ----
    short8 a_frag[2];
    #pragma unroll
    for (int mt = 0; mt < 2; ++mt) {
        float xe  = __shfl(x,  mt * 16 + nn, 64);
        float sce = __shfl(sc, mt * 16 + nn, 64);
        short8 af = {0, 0, 0, 0, 0, 0, 0, 0};
        if (q < 2) {
            #pragma unroll
            for (int jj = 0; jj < 8; ++jj) {
                float kf = (float)(q * 8 + jj);
                af[jj] = f2bf(__sinf(xe * kf) * sce);
            }
        }
        a_frag[mt] = af;
    }

    // ---- P2: h = ssp(rbf @ w1) -> s_hf (wave-private) ----
    {
        f32x4 z = {0.f, 0.f, 0.f, 0.f};
        #pragma unroll
        for (int nt = 0; nt < 4; ++nt) {
            short8 b = *(const short8*)&w1t_g[(16 * nt + nn) * 32 + q * 8];
            #pragma unroll
            for (int mt = 0; mt < 2; ++mt) {
                f32x4 h = __builtin_amdgcn_mfma_f32_16x16x32_bf16(a_frag[mt], b, z, 0, 0, 0);
                #pragma unroll
                for (int r = 0; r < 4; ++r)
                    s_hf[(16 * mt + 4 * q + r) * 72 + 16 * nt + nn] = f2bf(ssp_fast(h[r]));
            }
        }
    }

    // ---- P3: fr = h @ w2 accumulated in registers; then overwrite h ----
    {
        f32x4 facc[4][2];
        #pragma unroll
        for (int nt = 0; nt < 4; ++nt) {
            facc[nt][0] = (f32x4){0.f, 0.f, 0.f, 0.f};
            facc[nt][1] = (f32x4){0.f, 0.f, 0.f, 0.f};
            #pragma unroll
            for (int kc = 0; kc < 2; ++kc) {
                short8 b = *(const short8*)&w2t_g[(16 * nt + nn) * 64 + kc * 32 + q * 8];
                #pragma unroll
                for (int mt = 0; mt < 2; ++mt) {
                    short8 a = *(const short8*)&s_hf[(16 * mt + nn) * 72 + kc * 32 + q * 8];
                    facc[nt][mt] = __builtin_amdgcn_mfma_f32_16x16x32_bf16(a, b, facc[nt][mt], 0, 0, 0);
                }
            }
        }
        // all h reads issued & consumed; store f over the same region
        #pragma unroll
        for (int nt = 0; nt < 4; ++nt)
            #pragma unroll
            for (int mt = 0; mt < 2; ++mt)
                #pragma unroll
                for (int r = 0; r < 4; ++r)
                    s_hf[(16 * mt + 4 * q + r) * 72 + 16 * nt + nn] = f2bf(facc[nt][mt][r]);
    }

    // ---- P4: coupling over the wave's 32 edges; agg in REGISTERS ----
    float acc0a = 0.f, acc0b = 0.f;
    float P01[3] = {0.f, 0.f, 0.f};
    float P10[3] = {0.f, 0.f, 0.f};
    float P11[3] = {0.f, 0.f, 0.f};
    {
        #pragma unroll
        for (int g = 0; g < 8; ++g) {
            int cur = g & 1;
            #pragma unroll
            for (int u = 0; u < 4; ++u) {
                int el = g * 4 + u;
                float ryu = __shfl(ry, el, 64);
                float rzu = __shfl(rz, el, 64);
                float rxu = __shfl(rx, el, 64);
                float msku = __shfl(msk, el, 64);
                float f = bf2f(s_hf[el * 72 + lane]) * msku;
                float a0 = pv[cur][u].x, a1y = pv[cur][u].y;
                float a1z = pv[cur][u].z, a1x = pv[cur][u].w;

                float a0f = a0 * f;
                acc0a += a0f;
                acc0b = fmaf(f, a1y * ryu + a1z * rzu + a1x * rxu, acc0b);
                P01[0] = fmaf(a0f, ryu, P01[0]);
                P01[1] = fmaf(a0f, rzu, P01[1]);
                P01[2] = fmaf(a0f, rxu, P01[2]);
                P10[0] = fmaf(a1y, f, P10[0]);
                P10[1] = fmaf(a1z, f, P10[1]);
                P10[2] = fmaf(a1x, f, P10[2]);
                P11[0] = fmaf(a1z * rxu - a1x * rzu, f, P11[0]);  // cy
                P11[1] = fmaf(a1x * ryu - a1y * rxu, f, P11[1]);  // cz
                P11[2] = fmaf(a1y * rzu - a1z * ryu, f, P11[2]);  // cx
            }
            if (g < 6) {
                #pragma unroll
                for (int u = 0; u < 4; ++u) {
                    int jn = __shfl(j, (g + 2) * 4 + u, 64);
                    pv[cur][u] = ((const float4*)pre_t)[(size_t)jn * 64 + lane];
                }
            }
        }
    }
    __syncthreads();                                              // B1

    // ---- P5 overlays (all waves' h/f dead).  Fits in 18432 B:
    //   l0a [0, 4352)   16x136 bf16 (rows 0-3 valid)
    //   l1a [4352,10752) 16x200 bf16 (rows 0-11 valid)
    //   cout [10752,14848) 4x256 fp32
    //   g0t [0, 2304)   16x72 bf16 (rows 0-3)   -- over dead l0a, after B3
    //   g1t [2304, 4608) 16x72 bf16 (rows 0-11) -- over dead l0a/l1a
    short* l0a    = (short*)s_u;
    short* l1a    = (short*)(s_u + 4352);
    float* s_cout = (float*)(s_u + 10752);
    short* g0t    = (short*)s_u;
    short* g1t    = (short*)(s_u + 2304);

    // pack agg (registers) -> bf16 A tiles; lane == channel
    l0a[wave * 136 + lane]      = f2bf(acc0a);
    l0a[wave * 136 + 64 + lane] = f2bf(acc0b);
    #pragma unroll
    for (int m = 0; m < 3; ++m) {
        short* row = &l1a[(wave * 3 + m) * 200];
        row[lane]       = f2bf(P01[m]);
        row[64 + lane]  = f2bf(P10[m]);
        row[128 + lane] = f2bf(P11[m]);
    }
    __syncthreads();                                              // B2

    int col = 16 * wave + nn;
    // P5a: cout = ielin(agg, w_a) via MFMA
    {
        f32x4 acc0 = {0.f, 0.f, 0.f, 0.f};
        #pragma unroll
        for (int kc = 0; kc < 4; ++kc) {
            short8 b = *(const short8*)&w_a0t[col * 128 + kc * 32 + q * 8];
            short8 a = *(const short8*)&l0a[nn * 136 + kc * 32 + q * 8];
            acc0 = __builtin_amdgcn_mfma_f32_16x16x32_bf16(a, b, acc0, 0, 0, 0);
        }
        if (q == 0) {
            #pragma unroll
            for (int r = 0; r < 4; ++r)
                s_cout[r * 256 + col] = acc0[r];     // row r = node r
        }
        f32x4 acc1 = {0.f, 0.f, 0.f, 0.f};
        #pragma unroll
        for (int kc = 0; kc < 6; ++kc) {
            short8 b = *(const short8*)&w_a1t[col * 192 + kc * 32 + q * 8];
            short8 a = *(const short8*)&l1a[nn * 200 + kc * 32 + q * 8];
            acc1 = __builtin_amdgcn_mfma_f32_16x16x32_bf16(a, b, acc1, 0, 0, 0);
        }
        #pragma unroll
        for (int r = 0; r < 4; ++r) {
            int row = 4 * q + r;
            if (row < 12) {
                int nd = (int)((unsigned)row / 3u);
                int m = row - nd * 3;
                s_cout[nd * 256 + 64 + m * 64 + col] = acc1[r];
            }
        }
    }
    __syncthreads();                                              // B3

    // gate -> bf16 gated A-tiles (over dead l0a/l1a)
    #pragma unroll
    for (int n = 0; n < 4; ++n) {
        float v = s_cout[n * 256 + t];
        float g;
        if (wave == 0) {
            g = ssp_fast(v);
        } else {
            float c0 = s_cout[n * 256 + 64 + lane];
            float c1 = s_cout[n * 256 + 128 + lane];
            float c2 = s_cout[n * 256 + 192 + lane];
            g = ssp_fast(sqrtf(fmaf(c0, c0, fmaf(c1, c1, fmaf(c2, c2, 1e-12f)))));
        }
        float gv = v * g;
        if (wave == 0) g0t[n * 72 + lane] = f2bf(gv);
        else           g1t[(n * 3 + wave - 1) * 72 + lane] = f2bf(gv);
    }
    __syncthreads();                                              // B4

    // P5b: out = feat + ielin(gated, w_b) via MFMA
    {
        f32x4 acc0 = {0.f, 0.f, 0.f, 0.f};
        #pragma unroll
        for (int kc = 0; kc < 2; ++kc) {
            short8 b = *(const short8*)&w_b0t[col * 64 + kc * 32 + q * 8];
            short8 a = *(const short8*)&g0t[nn * 72 + kc * 32 + q * 8];
            acc0 = __builtin_amdgcn_mfma_f32_16x16x32_bf16(a, b, acc0, 0, 0, 0);
        }
        if (q == 0) {
            #pragma unroll
            for (int r = 0; r < 4; ++r) {
                size_t o = (size_t)(i0 + r) * 256 + col;
                out[o] = feat[o] + acc0[r];
            }
        }
        f32x4 acc1 = {0.f, 0.f, 0.f, 0.f};
        #pragma unroll
        for (int kc = 0; kc < 2; ++kc) {
            short8 b = *(const short8*)&w_b1t[col * 64 + kc * 32 + q * 8];
            short8 a = *(const short8*)&g1t[nn * 72 + kc * 32 + q * 8];
            acc1 = __builtin_amdgcn_mfma_f32_16x16x32_bf16(a, b, acc1, 0, 0, 0);
        }
        #pragma unroll
        for (int r = 0; r < 4; ++r) {
            int row = 4 * q + r;
            if (row < 12) {
                int nd = (int)((unsigned)row / 3u);
                int m = row - nd * 3;
                size_t o = (size_t)(i0 + nd) * 256 + 64 + m * 64 + col;
                out[o] = feat[o] + acc1[r];
            }
        }
    }
}

extern "C" void kernel_launch(void* const* d_in, const int* in_sizes, int n_in,
                              void* d_out, int out_size, void* d_ws, size_t ws_size,
                              hipStream_t stream) {
    const float* xyz     = (const float*)d_in[0];
    const float* feat    = (const float*)d_in[1];
    const float* w_f1    = (const float*)d_in[2];
    const float* w_f2    = (const float*)d_in[3];
    const float* w_pre0  = (const float*)d_in[4];
    const float* w_pre1  = (const float*)d_in[5];
    const float* w_a0    = (const float*)d_in[6];
    const float* w_a1    = (const float*)d_in[7];
    const float* w_b0    = (const float*)d_in[8];
    const float* w_b1    = (const float*)d_in[9];
    const int* src_idx   = (const int*)d_in[10];
    const int* edge_mask = (const int*)d_in[11];
    float* out = (float*)d_out;

    char* ws = (char*)d_ws;
    float* pre_t = (float*)ws;                          // 4 MB
    short* w1t   = (short*)(ws + 4194304);              // 4 KB
    short* w2t   = (short*)(ws + 4194304 + 4096);       // 8 KB
    short* w_a0t = (short*)(ws + 4194304 + 12288);      // 16 KB
    short* w_a1t = (short*)(ws + 4194304 + 28672);      // 24 KB
    short* w_b0t = (short*)(ws + 4194304 + 53248);      // 8 KB
    short* w_b1t = (short*)(ws + 4194304 + 61440);      // 8 KB

    pre_kernel<<<NN / 8, 256, 0, stream>>>(feat, w_pre0, w_pre1, pre_t,
                                           w_f1, w_f2, w_a0, w_a1, w_b0, w_b1,
                                           w1t, w2t, w_a0t, w_a1t, w_b0t, w_b1t);
    edge_kernel<<<NN / 4, 256, 0, stream>>>(xyz, feat, pre_t, w1t, w2t,
                                            w_a0t, w_a1t, w_b0t, w_b1t,
                                            src_idx, edge_mask, out);
}

// Round 16
// 108.106 us; speedup vs baseline: 1.0171x; 1.0171x over previous
//
#include <hip/hip_runtime.h>
#include <math.h>

#define NN 4096
#define MM 32
#define LOG2F_ 0.69314718055994530942f

typedef __attribute__((ext_vector_type(8))) short short8;
typedef __attribute__((ext_vector_type(4))) float f32x4;

__device__ __forceinline__ float ssp_fast(float x) {
    float sp = (x > 20.0f) ? x : __logf(1.0f + __expf(x));
    return sp - LOG2F_;
}

// float -> bf16 bits, round-to-nearest-even
__device__ __forceinline__ short f2bf(float x) {
    unsigned u = __float_as_uint(x);
    unsigned r = (u + 0x7FFFu + ((u >> 16) & 1u)) >> 16;
    return (short)r;
}
__device__ __forceinline__ float bf2f(short s) {
    return __uint_as_float(((unsigned)(unsigned short)s) << 16);
}

// K1: pre = ielin(feat, w_pre0, w_pre1) via MFMA, 8 nodes/block.
// Weight->bf16^T conversion spread across all blocks (<=1 elem/thread).
__global__ __launch_bounds__(256) void pre_kernel(
    const float* __restrict__ feat, const float* __restrict__ w0,
    const float* __restrict__ w1, float* __restrict__ pre_t,
    const float* __restrict__ w_f1, const float* __restrict__ w_f2,
    const float* __restrict__ w_a0, const float* __restrict__ w_a1,
    const float* __restrict__ w_b0, const float* __restrict__ w_b1,
    short* __restrict__ w1t, short* __restrict__ w2t,
    short* __restrict__ w_a0t, short* __restrict__ w_a1t,
    short* __restrict__ w_b0t, short* __restrict__ w_b1t)
{
    int t = threadIdx.x;
    int base = blockIdx.x * 8;
    int lane = t & 63, wave = t >> 6, q = lane >> 4, nn = lane & 15;

    // distributed weight transpose+convert: gid in [0, 34816)
    {
        int gid = blockIdx.x * 256 + t;
        if (gid < 2048) {
            int n = gid >> 5, k = gid & 31;
            w1t[gid] = (k < 16) ? f2bf(w_f1[k * 64 + n]) : (short)0;
        } else if (gid < 6144) {
            int idx = gid - 2048; int n = idx >> 6, k = idx & 63;
            w2t[idx] = f2bf(w_f2[k * 64 + n]);
        } else if (gid < 10240) {
            int idx = gid - 6144; int n = idx >> 6, k = idx & 63;
            w_b0t[idx] = f2bf(w_b0[k * 64 + n]);
        } else if (gid < 14336) {
            int idx = gid - 10240; int n = idx >> 6, k = idx & 63;
            w_b1t[idx] = f2bf(w_b1[k * 64 + n]);
        } else if (gid < 22528) {
            int idx = gid - 14336; int n = idx >> 7, k = idx & 127;
            w_a0t[idx] = f2bf(w_a0[k * 64 + n]);
        } else if (gid < 34816) {
            int idx = gid - 22528; int n = idx / 192, k = idx - n * 192;
            w_a1t[idx] = f2bf(w_a1[k * 64 + n]);
        }
    }

    __shared__ __align__(16) short s_a0[16 * 72];
    __shared__ __align__(16) short s_a1[2][16 * 72];
    __shared__ __align__(16) short s_w0[64 * 72];
    __shared__ __align__(16) short s_w1[64 * 72];
    __shared__ __align__(16) float s_po[8][256];

    for (int idx = t; idx < 512; idx += 256) {
        int r = 8 + (idx >> 6), k = idx & 63;
        s_a0[r * 72 + k] = 0;
        s_a1[1][r * 72 + k] = 0;
    }
    #pragma unroll 4
    for (int kk = 0; kk < 16; ++kk) {
        int k = wave * 16 + kk;
        s_w0[lane * 72 + k] = f2bf(w0[k * 64 + lane]);
        s_w1[lane * 72 + k] = f2bf(w1[k * 64 + lane]);
    }
    {
        const float4* f4 = (const float4*)(feat + (size_t)base * 256);
        #pragma unroll
        for (int rep = 0; rep < 2; ++rep) {
            int idx = t + rep * 256;
            float4 v = f4[idx];
            int node = idx >> 6, c = (idx & 63) * 4;
            short* dst;
            if (c < 64) {
                dst = &s_a0[node * 72 + c];
            } else {
                int mm = (c >> 6) - 1, ch = c & 63;
                int row = node * 3 + mm;
                dst = &s_a1[row >> 4][(row & 15) * 72 + ch];
            }
            dst[0] = f2bf(v.x); dst[1] = f2bf(v.y);
            dst[2] = f2bf(v.z); dst[3] = f2bf(v.w);
        }
    }
    __syncthreads();

    short8 bw0[2], bw1[2];
    #pragma unroll
    for (int kc = 0; kc < 2; ++kc) {
        bw0[kc] = *(const short8*)&s_w0[(16 * wave + nn) * 72 + kc * 32 + q * 8];
        bw1[kc] = *(const short8*)&s_w1[(16 * wave + nn) * 72 + kc * 32 + q * 8];
    }
    {
        f32x4 acc = {0.f, 0.f, 0.f, 0.f};
        #pragma unroll
        for (int kc = 0; kc < 2; ++kc) {
            short8 a = *(const short8*)&s_a0[nn * 72 + kc * 32 + q * 8];
            acc = __builtin_amdgcn_mfma_f32_16x16x32_bf16(a, bw0[kc], acc, 0, 0, 0);
        }
        if (q < 2) {
            #pragma unroll
            for (int r = 0; r < 4; ++r)
                s_po[4 * q + r][(16 * wave + nn) * 4 + 0] = acc[r];
        }
    }
    #pragma unroll
    for (int tile = 0; tile < 2; ++tile) {
        f32x4 acc = {0.f, 0.f, 0.f, 0.f};
        #pragma unroll
        for (int kc = 0; kc < 2; ++kc) {
            short8 a = *(const short8*)&s_a1[tile][nn * 72 + kc * 32 + q * 8];
            acc = __builtin_amdgcn_mfma_f32_16x16x32_bf16(a, bw1[kc], acc, 0, 0, 0);
        }
        #pragma unroll
        for (int r = 0; r < 4; ++r) {
            int row = tile * 16 + 4 * q + r;
            if (row < 24) {
                unsigned node = (unsigned)row / 3u;
                int mm = row - (int)node * 3;
                s_po[node][(16 * wave + nn) * 4 + 1 + mm] = acc[r];
            }
        }
    }
    __syncthreads();

    #pragma unroll
    for (int rep = 0; rep < 2; ++rep) {
        int idx = t + rep * 256;
        int node = idx >> 6, c4 = idx & 63;
        *(float4*)&pre_t[(size_t)(base + node) * 256 + c4 * 4] =
            *(const float4*)&s_po[node][c4 * 4];
    }
}

// K2: WAVE-AUTONOMOUS (R14 structure). 4 nodes/block; each wave owns one
// node (32 edges) end-to-end, no block barriers until P5. Radial B-fragments
// HOISTED to kernel start so their L2 latency overlaps geometry+sins.
// LDS 36 KB -> 4 blocks/CU; 4 barriers total.
__global__ __launch_bounds__(256, 4) void edge_kernel(
    const float* __restrict__ xyz, const float* __restrict__ feat,
    const float* __restrict__ pre_t,
    const short* __restrict__ w1t_g, const short* __restrict__ w2t_g,
    const short* __restrict__ w_a0t, const short* __restrict__ w_a1t,
    const short* __restrict__ w_b0t, const short* __restrict__ w_b1t,
    const int* __restrict__ src_idx, const int* __restrict__ edge_mask,
    float* __restrict__ out)
{
    int i0 = blockIdx.x * 4;
    int t = threadIdx.x;
    int lane = t & 63;
    int wave = t >> 6;
    int q = lane >> 4;
    int nn = lane & 15;

    __shared__ __align__(16) char s_u[36864];   // 4 x 9216 wave-private; P5 overlays
    short* s_h = (short*)(s_u + wave * 9216);           // 32 x 72 bf16
    short* s_f = (short*)(s_u + wave * 9216 + 4608);    // 32 x 72 bf16

    int node = i0 + wave;

    // ---- HOISTED radial B-fragments: issued first, consumed in P2/P3 ----
    short8 b1f[4], b2f[4][2];
    #pragma unroll
    for (int nt = 0; nt < 4; ++nt) {
        b1f[nt] = *(const short8*)&w1t_g[(16 * nt + nn) * 32 + q * 8];
        #pragma unroll
        for (int kc = 0; kc < 2; ++kc)
            b2f[nt][kc] = *(const short8*)&w2t_g[(16 * nt + nn) * 64 + kc * 32 + q * 8];
    }

    // ---- geometry: lane handles edge lane&31 (2-way redundant) ----
    int e = lane & 31;
    int j = src_idx[node * MM + e];
    float msk = (float)edge_mask[node * MM + e];
    float r0 = xyz[j * 3 + 0] - xyz[node * 3 + 0];
    float r1 = xyz[j * 3 + 1] - xyz[node * 3 + 1];
    float r2 = xyz[j * 3 + 2] - xyz[node * 3 + 2];
    float d = sqrtf(r0 * r0 + r1 * r1 + r2 * r2);
    float inv_d = 1.0f / d;
    float x = d * 0.2f;
    float env = 0.f;
    if (x < 1.f) {
        float x3 = x * x * x;
        env = 1.f - 10.f * x3 + 15.f * x3 * x - 6.f * x3 * x * x;
    }
    float sc = env * inv_d;
    float ry = r1 * inv_d, rz = r2 * inv_d, rx = r0 * inv_d;

    // ---- prefetch gather groups 0,1 (edges 0-7) ----
    float4 pv[2][4];
    #pragma unroll
    for (int u = 0; u < 4; ++u) {
        int ju = __shfl(j, u, 64);
        pv[0][u] = ((const float4*)pre_t)[(size_t)ju * 64 + lane];
    }
    #pragma unroll
    for (int u = 0; u < 4; ++u) {
        int ju = __shfl(j, 4 + u, 64);
        pv[1][u] = ((const float4*)pre_t)[(size_t)ju * 64 + lane];
    }

    // ---- rbf A-fragments in registers ----
    short8 a_frag[2];
    #pragma unroll
    for (int mt = 0; mt < 2; ++mt) {
        float xe  = __shfl(x,  mt * 16 + nn, 64);
        float sce = __shfl(sc, mt * 16 + nn, 64);
        short8 af = {0, 0, 0, 0, 0, 0, 0, 0};
        if (q < 2) {
            #pragma unroll
            for (int jj = 0; jj < 8; ++jj) {
                float kf = (float)(q * 8 + jj);
                af[jj] = f2bf(__sinf(xe * kf) * sce);
            }
        }
        a_frag[mt] = af;
    }

    // ---- P2: h = ssp(rbf @ w1); wave covers all 64 hidden cols ----
    {
        f32x4 z = {0.f, 0.f, 0.f, 0.f};
        #pragma unroll
        for (int nt = 0; nt < 4; ++nt) {
            #pragma unroll
            for (int mt = 0; mt < 2; ++mt) {
                f32x4 h = __builtin_amdgcn_mfma_f32_16x16x32_bf16(a_frag[mt], b1f[nt], z, 0, 0, 0);
                #pragma unroll
                for (int r = 0; r < 4; ++r)
                    s_h[(16 * mt + 4 * q + r) * 72 + 16 * nt + nn] = f2bf(ssp_fast(h[r]));
            }
        }
    }

    // ---- P3: fr = h @ w2 (wave-private; intra-wave lgkmcnt ordering) ----
    {
        #pragma unroll
        for (int nt = 0; nt < 4; ++nt) {
            f32x4 acc[2];
            acc[0] = (f32x4){0.f, 0.f, 0.f, 0.f};
            acc[1] = (f32x4){0.f, 0.f, 0.f, 0.f};
            #pragma unroll
            for (int kc = 0; kc < 2; ++kc) {
                #pragma unroll
                for (int mt = 0; mt < 2; ++mt) {
                    short8 a = *(const short8*)&s_h[(16 * mt + nn) * 72 + kc * 32 + q * 8];
                    acc[mt] = __builtin_amdgcn_mfma_f32_16x16x32_bf16(a, b2f[nt][kc], acc[mt], 0, 0, 0);
                }
            }
            #pragma unroll
            for (int mt = 0; mt < 2; ++mt)
                #pragma unroll
                for (int r = 0; r < 4; ++r)
                    s_f[(16 * mt + 4 * q + r) * 72 + 16 * nt + nn] = f2bf(acc[mt][r]);
        }
    }

    // ---- P4: coupling over the wave's 32 edges; agg in REGISTERS ----
    float acc0a = 0.f, acc0b = 0.f;
    float P01[3] = {0.f, 0.f, 0.f};
    float P10[3] = {0.f, 0.f, 0.f};
    float P11[3] = {0.f, 0.f, 0.f};
    {
        #pragma unroll
        for (int g = 0; g < 8; ++g) {
            int cur = g & 1;
            #pragma unroll
            for (int u = 0; u < 4; ++u) {
                int el = g * 4 + u;
                float ryu = __shfl(ry, el, 64);
                float rzu = __shfl(rz, el, 64);
                float rxu = __shfl(rx, el, 64);
                float msku = __shfl(msk, el, 64);
                float f = bf2f(s_f[el * 72 + lane]) * msku;
                float a0 = pv[cur][u].x, a1y = pv[cur][u].y;
                float a1z = pv[cur][u].z, a1x = pv[cur][u].w;

                float a0f = a0 * f;
                acc0a += a0f;
                acc0b = fmaf(f, a1y * ryu + a1z * rzu + a1x * rxu, acc0b);
                P01[0] = fmaf(a0f, ryu, P01[0]);
                P01[1] = fmaf(a0f, rzu, P01[1]);
                P01[2] = fmaf(a0f, rxu, P01[2]);
                P10[0] = fmaf(a1y, f, P10[0]);
                P10[1] = fmaf(a1z, f, P10[1]);
                P10[2] = fmaf(a1x, f, P10[2]);
                P11[0] = fmaf(a1z * rxu - a1x * rzu, f, P11[0]);  // cy
                P11[1] = fmaf(a1x * ryu - a1y * rxu, f, P11[1]);  // cz
                P11[2] = fmaf(a1y * rzu - a1z * ryu, f, P11[2]);  // cx
            }
            if (g < 6) {   // prefetch group g+2 into the buffer just freed
                #pragma unroll
                for (int u = 0; u < 4; ++u) {
                    int jn = __shfl(j, (g + 2) * 4 + u, 64);
                    pv[cur][u] = ((const float4*)pre_t)[(size_t)jn * 64 + lane];
                }
            }
        }
    }
    __syncthreads();                                              // B1

    // ---- P5 overlays (all waves' h/f dead) ----
    short* l0a    = (short*)s_u;               // 16x136 (rows 0-3 valid)
    short* l1a    = (short*)(s_u + 4352);      // 16x200 (rows 0-11 valid)
    short* g0t    = (short*)(s_u + 10752);     // 16x72 (rows 0-3 valid)
    short* g1t    = (short*)(s_u + 13056);     // 16x72 (rows 0-11 valid)
    float* s_cout = (float*)(s_u + 15360);     // 4x256 fp32

    // pack agg (registers) -> bf16 A tiles; lane == channel
    l0a[wave * 136 + lane]      = f2bf(acc0a);
    l0a[wave * 136 + 64 + lane] = f2bf(acc0b);
    #pragma unroll
    for (int m = 0; m < 3; ++m) {
        short* row = &l1a[(wave * 3 + m) * 200];
        row[lane]       = f2bf(P01[m]);
        row[64 + lane]  = f2bf(P10[m]);
        row[128 + lane] = f2bf(P11[m]);
    }
    __syncthreads();                                              // B2

    int col = 16 * wave + nn;
    // P5a: cout = ielin(agg, w_a) via MFMA
    {
        f32x4 acc0 = {0.f, 0.f, 0.f, 0.f};
        #pragma unroll
        for (int kc = 0; kc < 4; ++kc) {
            short8 b = *(const short8*)&w_a0t[col * 128 + kc * 32 + q * 8];
            short8 a = *(const short8*)&l0a[nn * 136 + kc * 32 + q * 8];
            acc0 = __builtin_amdgcn_mfma_f32_16x16x32_bf16(a, b, acc0, 0, 0, 0);
        }
        if (q == 0) {
            #pragma unroll
            for (int r = 0; r < 4; ++r)
                s_cout[r * 256 + col] = acc0[r];     // row r = node r
        }
        f32x4 acc1 = {0.f, 0.f, 0.f, 0.f};
        #pragma unroll
        for (int kc = 0; kc < 6; ++kc) {
            short8 b = *(const short8*)&w_a1t[col * 192 + kc * 32 + q * 8];
            short8 a = *(const short8*)&l1a[nn * 200 + kc * 32 + q * 8];
            acc1 = __builtin_amdgcn_mfma_f32_16x16x32_bf16(a, b, acc1, 0, 0, 0);
        }
        #pragma unroll
        for (int r = 0; r < 4; ++r) {
            int row = 4 * q + r;
            if (row < 12) {
                int nd = (int)((unsigned)row / 3u);
                int m = row - nd * 3;
                s_cout[nd * 256 + 64 + m * 64 + col] = acc1[r];
            }
        }
    }
    __syncthreads();                                              // B3

    // gate -> bf16 gated A-tiles
    #pragma unroll
    for (int n = 0; n < 4; ++n) {
        float v = s_cout[n * 256 + t];
        float g;
        if (wave == 0) {
            g = ssp_fast(v);
        } else {
            float c0 = s_cout[n * 256 + 64 + lane];
            float c1 = s_cout[n * 256 + 128 + lane];
            float c2 = s_cout[n * 256 + 192 + lane];
            g = ssp_fast(sqrtf(fmaf(c0, c0, fmaf(c1, c1, fmaf(c2, c2, 1e-12f)))));
        }
        float gv = v * g;
        if (wave == 0) g0t[n * 72 + lane] = f2bf(gv);
        else           g1t[(n * 3 + wave - 1) * 72 + lane] = f2bf(gv);
    }
    __syncthreads();                                              // B4

    // P5b: out = feat + ielin(gated, w_b) via MFMA
    {
        f32x4 acc0 = {0.f, 0.f, 0.f, 0.f};
        #pragma unroll
        for (int kc = 0; kc < 2; ++kc) {
            short8 b = *(const short8*)&w_b0t[col * 64 + kc * 32 + q * 8];
            short8 a = *(const short8*)&g0t[nn * 72 + kc * 32 + q * 8];
            acc0 = __builtin_amdgcn_mfma_f32_16x16x32_bf16(a, b, acc0, 0, 0, 0);
        }
        if (q == 0) {
            #pragma unroll
            for (int r = 0; r < 4; ++r) {
                size_t o = (size_t)(i0 + r) * 256 + col;
                out[o] = feat[o] + acc0[r];
            }
        }
        f32x4 acc1 = {0.f, 0.f, 0.f, 0.f};
        #pragma unroll
        for (int kc = 0; kc < 2; ++kc) {
            short8 b = *(const short8*)&w_b1t[col * 64 + kc * 32 + q * 8];
            short8 a = *(const short8*)&g1t[nn * 72 + kc * 32 + q * 8];
            acc1 = __builtin_amdgcn_mfma_f32_16x16x32_bf16(a, b, acc1, 0, 0, 0);
        }
        #pragma unroll
        for (int r = 0; r < 4; ++r) {
            int row = 4 * q + r;
            if (row < 12) {
                int nd = (int)((unsigned)row / 3u);
                int m = row - nd * 3;
                size_t o = (size_t)(i0 + nd) * 256 + 64 + m * 64 + col;
                out[o] = feat[o] + acc1[r];
            }
        }
    }
}

extern "C" void kernel_launch(void* const* d_in, const int* in_sizes, int n_in,
                              void* d_out, int out_size, void* d_ws, size_t ws_size,
                              hipStream_t stream) {
    const float* xyz     = (const float*)d_in[0];
    const float* feat    = (const float*)d_in[1];
    const float* w_f1    = (const float*)d_in[2];
    const float* w_f2    = (const float*)d_in[3];
    const float* w_pre0  = (const float*)d_in[4];
    const float* w_pre1  = (const float*)d_in[5];
    const float* w_a0    = (const float*)d_in[6];
    const float* w_a1    = (const float*)d_in[7];
    const float* w_b0    = (const float*)d_in[8];
    const float* w_b1    = (const float*)d_in[9];
    const int* src_idx   = (const int*)d_in[10];
    const int* edge_mask = (const int*)d_in[11];
    float* out = (float*)d_out;

    char* ws = (char*)d_ws;
    float* pre_t = (float*)ws;                          // 4 MB
    short* w1t   = (short*)(ws + 4194304);              // 4 KB
    short* w2t   = (short*)(ws + 4194304 + 4096);       // 8 KB
    short* w_a0t = (short*)(ws + 4194304 + 12288);      // 16 KB
    short* w_a1t = (short*)(ws + 4194304 + 28672);      // 24 KB
    short* w_b0t = (short*)(ws + 4194304 + 53248);      // 8 KB
    short* w_b1t = (short*)(ws + 4194304 + 61440);      // 8 KB

    pre_kernel<<<NN / 8, 256, 0, stream>>>(feat, w_pre0, w_pre1, pre_t,
                                           w_f1, w_f2, w_a0, w_a1, w_b0, w_b1,
                                           w1t, w2t, w_a0t, w_a1t, w_b0t, w_b1t);
    edge_kernel<<<NN / 4, 256, 0, stream>>>(xyz, feat, pre_t, w1t, w2t,
                                            w_a0t, w_a1t, w_b0t, w_b1t,
                                            src_idx, edge_mask, out);
}